// Round 1
// baseline (871.301 us; speedup 1.0000x reference)
//
#include <hip/hip_runtime.h>
#include <math.h>

#define NN 40000
#define NE 640000
#define NTOT (NE + NN)
#define D 128
#define NH 4
#define NC 32
#define NEG 0.2f

// ---------------- zero out + denom ----------------
__global__ void k_zero(float* __restrict__ out, float* __restrict__ denom) {
  int i = blockIdx.x * blockDim.x + threadIdx.x;
  int stride = gridDim.x * blockDim.x;
  for (int j = i; j < NN * D; j += stride) out[j] = 0.f;
  for (int j = i; j < NN * NH; j += stride) denom[j] = 0.f;
}

// ---------------- per-type constants (1 block, 512 threads) ----------------
// wq_eff[h][d] = sum_c att_i[h,c] * Wq[h*32+c][d]   (and wk_eff with att_j/Wk)
// ev[t][o]   = (Wv @ eemb[t])[o]      vemb[t][o] = (Wv @ nemb[t])[o]
// a_et[t][h] = wk_eff[h] . eemb[t]    aqt/akt[t][h] = wq/wk_eff[h] . nemb[t]
// WvT[d][o]  = Wv[o][d]   (transposed copy for coalesced register fill in k_xv)
__global__ void k_consts(const float* __restrict__ Wq, const float* __restrict__ Wk,
                         const float* __restrict__ Wv, const float* __restrict__ att_i,
                         const float* __restrict__ att_j,
                         const float* __restrict__ nemb, const float* __restrict__ eemb,
                         float* __restrict__ wq_eff, float* __restrict__ wk_eff,
                         float* __restrict__ ev, float* __restrict__ vemb,
                         float* __restrict__ a_et, float* __restrict__ aqt,
                         float* __restrict__ akt, float* __restrict__ WvT) {
  __shared__ float wq_s[512], wk_s[512];
  int t = threadIdx.x;
  {
    int h = t >> 7, d = t & 127;
    float sq = 0.f, sk = 0.f;
    for (int c = 0; c < NC; ++c) {
      sq += att_i[h * NC + c] * Wq[(h * NC + c) * D + d];
      sk += att_j[h * NC + c] * Wk[(h * NC + c) * D + d];
    }
    wq_eff[t] = sq; wk_eff[t] = sk; wq_s[t] = sq; wk_s[t] = sk;
  }
  // transpose Wv
  for (int i = t; i < D * D; i += 512) {
    int o = i >> 7, d = i & 127;
    WvT[d * D + o] = Wv[i];
  }
  __syncthreads();
  for (int i = t; i < 8 * D; i += 512) {
    int ty = i >> 7, o = i & 127;
    float se = 0.f, sn = 0.f;
    for (int dd = 0; dd < D; ++dd) {
      float w = Wv[o * D + dd];
      se += w * eemb[ty * D + dd];
      sn += w * nemb[ty * D + dd];
    }
    ev[i] = se; vemb[i] = sn;
  }
  if (t < 32) {
    int ty = t >> 2, hh = t & 3;
    float se = 0.f, sq2 = 0.f, sk2 = 0.f;
    for (int dd = 0; dd < D; ++dd) {
      se  += wk_s[hh * D + dd] * eemb[ty * D + dd];
      sq2 += wq_s[hh * D + dd] * nemb[ty * D + dd];
      sk2 += wk_s[hh * D + dd] * nemb[ty * D + dd];
    }
    a_et[t] = se; aqt[t] = sq2; akt[t] = sk2;
  }
}

// ---------------- V projection: xv[n][o] = Wv[o]·x[n] + vemb[nt[n]][o] ----------------
// Thread t owns output channel o=t; holds Wv row o in 128 VGPRs.
// x row address is block-uniform -> compiler emits scalar (s_load) broadcasts.
#define XV_BLOCKS 500
__global__ __launch_bounds__(128) void k_xv(const float* __restrict__ x,
        const int* __restrict__ node_type, const float* __restrict__ WvT,
        const float* __restrict__ vemb, float* __restrict__ xv) {
  int t = threadIdx.x;
  float w[128];
#pragma unroll
  for (int i = 0; i < 128; ++i) w[i] = WvT[i * D + t];  // coalesced across lanes
  int npb = (NN + XV_BLOCKS - 1) / XV_BLOCKS;           // 80
  int n0 = blockIdx.x * npb;
  int n1 = min(n0 + npb, NN);
  for (int n = n0; n < n1; ++n) {
    const float* __restrict__ xr = x + (size_t)n * D;
    float acc = 0.f;
#pragma unroll
    for (int i = 0; i < 128; ++i) acc = fmaf(w[i], xr[i], acc);
    int nt = node_type[n];
    xv[(size_t)n * D + t] = acc + vemb[nt * D + t];
  }
}

// ---------------- aq/ak: one wave per node, butterfly reduce ----------------
__global__ __launch_bounds__(256) void k_aqak(const float* __restrict__ x,
        const int* __restrict__ node_type,
        const float* __restrict__ wq_eff, const float* __restrict__ wk_eff,
        const float* __restrict__ aqt, const float* __restrict__ akt,
        float* __restrict__ aq, float* __restrict__ ak) {
  int wid = (int)((blockIdx.x * blockDim.x + threadIdx.x) >> 6);
  int l = threadIdx.x & 63;
  if (wid >= NN) return;
  const float* __restrict__ xr = x + (size_t)wid * D;
  float x0 = xr[l], x1 = xr[l + 64];
  float p[8];
#pragma unroll
  for (int j = 0; j < 8; ++j) {
    const float* __restrict__ wrow = (j < 4) ? (wq_eff + j * D) : (wk_eff + (j - 4) * D);
    p[j] = wrow[l] * x0 + wrow[l + 64] * x1;
  }
#pragma unroll
  for (int j = 0; j < 8; ++j) {
#pragma unroll
    for (int off = 32; off >= 1; off >>= 1) p[j] += __shfl_xor(p[j], off, 64);
  }
  if (l == 0) {
    int nt = node_type[wid];
#pragma unroll
    for (int h = 0; h < NH; ++h) {
      aq[wid * NH + h] = p[h]     + aqt[nt * NH + h];
      ak[wid * NH + h] = p[4 + h] + akt[nt * NH + h];
    }
  }
}

// ---------------- edge pass: one wave per edge (incl. self-loops) ----------------
// lane l handles channels 2l, 2l+1 (head = l>>4). Unnormalized scatter:
//   out[dst] += p * (xv[src] + ev[et]);   denom[dst,h] += p
__global__ __launch_bounds__(256) void k_edge(const int* __restrict__ ei,
        const int* __restrict__ etype,
        const float* __restrict__ aq, const float* __restrict__ ak,
        const float* __restrict__ a_et, const float* __restrict__ xv,
        const float* __restrict__ ev, float* __restrict__ out,
        float* __restrict__ denom) {
  int e = (int)(((long long)blockIdx.x * blockDim.x + threadIdx.x) >> 6);
  int l = threadIdx.x & 63;
  if (e >= NTOT) return;
  int src, dst, et;
  if (e < NE) { src = ei[e]; dst = ei[NE + e]; et = etype[e]; }
  else        { src = dst = e - NE; et = 0; }  // self-loop, EDGE_TYPE_SELF=0
  int h = l >> 4;
  float s = aq[dst * NH + h] + ak[src * NH + h] + a_et[et * NH + h];
  s = (s > 0.f) ? s : NEG * s;
  float p = __expf(s);
  const float2* __restrict__ xvr = (const float2*)(xv + (size_t)src * D);
  const float2* __restrict__ evr = (const float2*)(ev + et * D);
  float2 v = xvr[l];
  float2 ee = evr[l];
  float* outr = out + (size_t)dst * D;
  atomicAdd(&outr[2 * l],     p * (v.x + ee.x));
  atomicAdd(&outr[2 * l + 1], p * (v.y + ee.y));
  if ((l & 15) == 0) atomicAdd(&denom[dst * NH + h], p);
}

// ---------------- finalize: divide by denom, add bias ----------------
__global__ void k_final(float* __restrict__ out, const float* __restrict__ denom,
                        const float* __restrict__ bias) {
  int idx = blockIdx.x * blockDim.x + threadIdx.x;
  if (idx >= NN * D) return;
  int n = idx >> 7, c = idx & 127;
  out[idx] = out[idx] / (denom[n * NH + (c >> 5)] + 1e-16f) + bias[c];
}

extern "C" void kernel_launch(void* const* d_in, const int* in_sizes, int n_in,
                              void* d_out, int out_size, void* d_ws, size_t ws_size,
                              hipStream_t stream) {
  const float* x      = (const float*)d_in[0];
  const int*   ei     = (const int*)d_in[1];
  const int*   ntype  = (const int*)d_in[2];
  const int*   etype  = (const int*)d_in[3];
  const float* Wq     = (const float*)d_in[4];
  const float* Wk     = (const float*)d_in[5];
  const float* Wv     = (const float*)d_in[6];
  const float* att_i  = (const float*)d_in[7];
  const float* att_j  = (const float*)d_in[8];
  const float* bias   = (const float*)d_in[9];
  const float* nemb   = (const float*)d_in[10];
  const float* eemb   = (const float*)d_in[11];
  float* out = (float*)d_out;

  float* ws     = (float*)d_ws;
  float* xv     = ws;                       // NN*128
  float* aq     = xv + (size_t)NN * D;      // NN*4
  float* ak     = aq + NN * NH;             // NN*4
  float* denom  = ak + NN * NH;             // NN*4
  float* wq_eff = denom + NN * NH;          // 512
  float* wk_eff = wq_eff + 512;             // 512
  float* ev     = wk_eff + 512;             // 1024
  float* vemb   = ev + 1024;                // 1024
  float* a_et   = vemb + 1024;              // 32
  float* aqt    = a_et + 32;                // 32
  float* akt    = aqt + 32;                 // 32
  float* WvT    = akt + 32;                 // 16384

  k_zero<<<dim3(1024), dim3(256), 0, stream>>>(out, denom);
  k_consts<<<dim3(1), dim3(512), 0, stream>>>(Wq, Wk, Wv, att_i, att_j, nemb, eemb,
                                              wq_eff, wk_eff, ev, vemb, a_et, aqt, akt, WvT);
  k_xv<<<dim3(XV_BLOCKS), dim3(128), 0, stream>>>(x, ntype, WvT, vemb, xv);
  k_aqak<<<dim3((NN + 3) / 4), dim3(256), 0, stream>>>(x, ntype, wq_eff, wk_eff, aqt, akt, aq, ak);
  k_edge<<<dim3((NTOT + 3) / 4), dim3(256), 0, stream>>>(ei, etype, aq, ak, a_et, xv, ev, out, denom);
  k_final<<<dim3((NN * D + 255) / 256), dim3(256), 0, stream>>>(out, denom, bias);
}

// Round 2
// 454.417 us; speedup vs baseline: 1.9174x; 1.9174x over previous
//
#include <hip/hip_runtime.h>
#include <math.h>

#define NN 40000
#define NE 640000
#define NTOT (NE + NN)
#define D 128
#define NH 4
#define NC 32
#define NEG 0.2f

// ---------------- per-type constants (1 block, 512 threads) ----------------
// wq_eff[h][d] = sum_c att_i[h,c]*Wq[h*32+c][d]  (wk_eff with att_j/Wk)
// WvT[d][o] = Wv[o][d]
// ev[t][o] = (Wv@eemb[t])[o]   vemb[t][o] = (Wv@nemb[t])[o]
// a_et[t][h] = wk_eff[h].eemb[t]   aqt/akt[t][h] = wq/wk_eff[h].nemb[t]
__global__ void k_consts(const float* __restrict__ Wq, const float* __restrict__ Wk,
                         const float* __restrict__ Wv, const float* __restrict__ att_i,
                         const float* __restrict__ att_j,
                         const float* __restrict__ nemb, const float* __restrict__ eemb,
                         float* __restrict__ wq_eff, float* __restrict__ wk_eff,
                         float* __restrict__ ev, float* __restrict__ vemb,
                         float* __restrict__ a_et, float* __restrict__ aqt,
                         float* __restrict__ akt, float* __restrict__ WvT) {
  int t = threadIdx.x;
  {
    int h = t >> 7, d = t & 127;
    float sq = 0.f, sk = 0.f;
    for (int c = 0; c < NC; ++c) {
      sq += att_i[h * NC + c] * Wq[(h * NC + c) * D + d];
      sk += att_j[h * NC + c] * Wk[(h * NC + c) * D + d];
    }
    wq_eff[t] = sq; wk_eff[t] = sk;
  }
  // transpose Wv -> WvT (coalesced read)
  for (int i = t; i < D * D; i += 512) {
    int o = i >> 7, d = i & 127;
    WvT[d * D + o] = Wv[i];
  }
  __syncthreads();  // block-scope mem fence: WvT/wq_eff/wk_eff visible below
  // ev/vemb via WvT: lanes over o -> coalesced; eemb/nemb broadcast
  {
    int o = t & 127, tyg = t >> 7;
    for (int ty = tyg; ty < 8; ty += 4) {
      float se = 0.f, sn = 0.f;
      for (int dd = 0; dd < D; ++dd) {
        float w = WvT[dd * D + o];
        se = fmaf(w, eemb[ty * D + dd], se);
        sn = fmaf(w, nemb[ty * D + dd], sn);
      }
      ev[ty * D + o] = se; vemb[ty * D + o] = sn;
    }
  }
  if (t < 32) {
    int ty = t >> 2, hh = t & 3;
    float se = 0.f, sq2 = 0.f, sk2 = 0.f;
    for (int dd = 0; dd < D; ++dd) {
      se  += wk_eff[hh * D + dd] * eemb[ty * D + dd];
      sq2 += wq_eff[hh * D + dd] * nemb[ty * D + dd];
      sk2 += wk_eff[hh * D + dd] * nemb[ty * D + dd];
    }
    a_et[t] = se; aqt[t] = sq2; akt[t] = sk2;
  }
}

// ---------------- CSR build ----------------
__global__ void k_initcnt(int* __restrict__ counts) {
  int i = blockIdx.x * blockDim.x + threadIdx.x;
  if (i < NN) counts[i] = 1;  // self-loop
}

__global__ void k_hist(const int* __restrict__ ei, int* __restrict__ counts) {
  int e = blockIdx.x * blockDim.x + threadIdx.x;
  if (e < NE) atomicAdd(&counts[ei[NE + e]], 1);
}

// single block, 1024 threads, 40 elems each (exclusive scan -> rowptr, cursor)
__global__ __launch_bounds__(1024) void k_scan(const int* __restrict__ counts,
                                               int* __restrict__ rowptr,
                                               int* __restrict__ cursor) {
  __shared__ int sdata[1024];
  int t = threadIdx.x;
  int base = t * 40;
  int total = 0;
  int local[40];
#pragma unroll
  for (int j = 0; j < 40; ++j) {
    int idx = base + j;
    int c = (idx < NN) ? counts[idx] : 0;
    local[j] = total;  // exclusive within chunk
    total += c;
  }
  sdata[t] = total;
  // Hillis-Steele inclusive scan over 1024 totals
  for (int off = 1; off < 1024; off <<= 1) {
    __syncthreads();
    int v = (t >= off) ? sdata[t - off] : 0;
    __syncthreads();
    sdata[t] += v;
  }
  __syncthreads();
  int offset = sdata[t] - total;  // exclusive across chunks
#pragma unroll
  for (int j = 0; j < 40; ++j) {
    int idx = base + j;
    if (idx < NN) {
      int r = offset + local[j];
      rowptr[idx] = r;
      cursor[idx] = r;
    }
  }
  if (base <= NN - 1 && base + 40 >= NN) rowptr[NN] = offset + total;
}

// scatter edges (incl. self-loops) into CSR slots; pack src|et<<16 (N<2^16)
__global__ void k_scatter(const int* __restrict__ ei, const int* __restrict__ etype,
                          int* __restrict__ cursor, unsigned* __restrict__ packed) {
  int i = blockIdx.x * blockDim.x + threadIdx.x;
  if (i >= NTOT) return;
  int dst; unsigned rec;
  if (i < NE) {
    dst = ei[NE + i];
    rec = (unsigned)ei[i] | ((unsigned)etype[i] << 16);
  } else {
    dst = i - NE;
    rec = (unsigned)dst;  // EDGE_TYPE_SELF = 0
  }
  int pos = atomicAdd(&cursor[dst], 1);
  packed[pos] = rec;
}

// ---------------- V projection: xv[n][o] = Wv[o]·x[n] + vemb[nt[n]][o] ----------------
#define XV_BLOCKS 500
__global__ __launch_bounds__(128) void k_xv(const float* __restrict__ x,
        const int* __restrict__ node_type, const float* __restrict__ WvT,
        const float* __restrict__ vemb, float* __restrict__ xv) {
  int t = threadIdx.x;
  float w[128];
#pragma unroll
  for (int i = 0; i < 128; ++i) w[i] = WvT[i * D + t];
  int npb = (NN + XV_BLOCKS - 1) / XV_BLOCKS;
  int n0 = blockIdx.x * npb;
  int n1 = min(n0 + npb, NN);
  for (int n = n0; n < n1; ++n) {
    const float* __restrict__ xr = x + (size_t)n * D;
    float acc = 0.f;
#pragma unroll
    for (int i = 0; i < 128; ++i) acc = fmaf(w[i], xr[i], acc);
    int nt = node_type[n];
    xv[(size_t)n * D + t] = acc + vemb[nt * D + t];
  }
}

// ---------------- aq/ak: one wave per node, butterfly reduce ----------------
__global__ __launch_bounds__(256) void k_aqak(const float* __restrict__ x,
        const int* __restrict__ node_type,
        const float* __restrict__ wq_eff, const float* __restrict__ wk_eff,
        const float* __restrict__ aqt, const float* __restrict__ akt,
        float* __restrict__ aq, float* __restrict__ ak) {
  int wid = (int)((blockIdx.x * blockDim.x + threadIdx.x) >> 6);
  int l = threadIdx.x & 63;
  if (wid >= NN) return;
  const float* __restrict__ xr = x + (size_t)wid * D;
  float x0 = xr[l], x1 = xr[l + 64];
  float p[8];
#pragma unroll
  for (int j = 0; j < 8; ++j) {
    const float* __restrict__ wrow = (j < 4) ? (wq_eff + j * D) : (wk_eff + (j - 4) * D);
    p[j] = wrow[l] * x0 + wrow[l + 64] * x1;
  }
#pragma unroll
  for (int j = 0; j < 8; ++j) {
#pragma unroll
    for (int off = 32; off >= 1; off >>= 1) p[j] += __shfl_xor(p[j], off, 64);
  }
  if (l == 0) {
    int nt = node_type[wid];
#pragma unroll
    for (int h = 0; h < NH; ++h) {
      aq[wid * NH + h] = p[h]     + aqt[nt * NH + h];
      ak[wid * NH + h] = p[4 + h] + akt[nt * NH + h];
    }
  }
}

// ---------------- gather: one wave per dst node, no atomics ----------------
// lane l owns channels 2l,2l+1; head h = l>>4. out = (Σ p·(xv[src]+ev[et]))/Σp + bias
__global__ __launch_bounds__(256) void k_gather(const int* __restrict__ rowptr,
        const unsigned* __restrict__ packed,
        const float* __restrict__ aq, const float* __restrict__ ak,
        const float* __restrict__ a_et, const float* __restrict__ xv,
        const float* __restrict__ ev, const float* __restrict__ bias,
        float* __restrict__ out) {
  int n = (int)((blockIdx.x * blockDim.x + threadIdx.x) >> 6);
  int l = threadIdx.x & 63;
  if (n >= NN) return;
  int h = l >> 4;
  float aqh = aq[n * NH + h];
  int e0 = rowptr[n], e1 = rowptr[n + 1];
  const float2* __restrict__ xv2 = (const float2*)xv;
  const float2* __restrict__ ev2 = (const float2*)ev;
  float ax = 0.f, ay = 0.f, dsum = 0.f;
#pragma unroll 4
  for (int e = e0; e < e1; ++e) {
    unsigned rec = packed[e];          // wave-uniform broadcast load
    int src = (int)(rec & 0xFFFFu);
    int et  = (int)(rec >> 16);
    float s = aqh + ak[src * NH + h] + a_et[et * NH + h];
    s = (s > 0.f) ? s : NEG * s;
    float p = __expf(s);
    float2 v  = xv2[src * 64 + l];
    float2 ee = ev2[et * 64 + l];
    ax = fmaf(p, v.x + ee.x, ax);
    ay = fmaf(p, v.y + ee.y, ay);
    dsum += p;
  }
  float inv = 1.f / (dsum + 1e-16f);
  out[(size_t)n * D + 2 * l]     = ax * inv + bias[2 * l];
  out[(size_t)n * D + 2 * l + 1] = ay * inv + bias[2 * l + 1];
}

extern "C" void kernel_launch(void* const* d_in, const int* in_sizes, int n_in,
                              void* d_out, int out_size, void* d_ws, size_t ws_size,
                              hipStream_t stream) {
  const float* x      = (const float*)d_in[0];
  const int*   ei     = (const int*)d_in[1];
  const int*   ntype  = (const int*)d_in[2];
  const int*   etype  = (const int*)d_in[3];
  const float* Wq     = (const float*)d_in[4];
  const float* Wk     = (const float*)d_in[5];
  const float* Wv     = (const float*)d_in[6];
  const float* att_i  = (const float*)d_in[7];
  const float* att_j  = (const float*)d_in[8];
  const float* bias   = (const float*)d_in[9];
  const float* nemb   = (const float*)d_in[10];
  const float* eemb   = (const float*)d_in[11];
  float* out = (float*)d_out;

  float* ws     = (float*)d_ws;
  float* xv     = ws;                         // NN*128
  float* aq     = xv + (size_t)NN * D;        // NN*4
  float* ak     = aq + NN * NH;               // NN*4
  float* wq_eff = ak + NN * NH;               // 512
  float* wk_eff = wq_eff + 512;               // 512
  float* ev     = wk_eff + 512;               // 1024
  float* vemb   = ev + 1024;                  // 1024
  float* a_et   = vemb + 1024;                // 32
  float* aqt    = a_et + 32;                  // 32
  float* akt    = aqt + 32;                   // 32
  float* WvT    = akt + 32;                   // 16384
  int*   counts = (int*)(WvT + D * D);        // NN
  int*   rowptr = counts + NN;                // NN+1
  int*   cursor = rowptr + NN + 1;            // NN
  unsigned* packed = (unsigned*)(cursor + NN);// NTOT

  k_consts<<<dim3(1), dim3(512), 0, stream>>>(Wq, Wk, Wv, att_i, att_j, nemb, eemb,
                                              wq_eff, wk_eff, ev, vemb, a_et, aqt, akt, WvT);
  k_initcnt<<<dim3((NN + 255) / 256), dim3(256), 0, stream>>>(counts);
  k_hist<<<dim3((NE + 255) / 256), dim3(256), 0, stream>>>(ei, counts);
  k_scan<<<dim3(1), dim3(1024), 0, stream>>>(counts, rowptr, cursor);
  k_scatter<<<dim3((NTOT + 255) / 256), dim3(256), 0, stream>>>(ei, etype, cursor, packed);
  k_xv<<<dim3(XV_BLOCKS), dim3(128), 0, stream>>>(x, ntype, WvT, vemb, xv);
  k_aqak<<<dim3((NN + 3) / 4), dim3(256), 0, stream>>>(x, ntype, wq_eff, wk_eff, aqt, akt, aq, ak);
  k_gather<<<dim3((NN + 3) / 4), dim3(256), 0, stream>>>(rowptr, packed, aq, ak, a_et, xv, ev, bias, out);
}

// Round 3
// 413.928 us; speedup vs baseline: 2.1050x; 1.0978x over previous
//
#include <hip/hip_runtime.h>
#include <math.h>

#define NN 40000
#define NE 640000
#define NTOT (NE + NN)
#define D 128
#define NH 4
#define NC 32
#define NEG 0.2f

// ---------------- per-type constants (1 block, 512 threads) ----------------
__global__ void k_consts(const float* __restrict__ Wq, const float* __restrict__ Wk,
                         const float* __restrict__ Wv, const float* __restrict__ att_i,
                         const float* __restrict__ att_j,
                         const float* __restrict__ nemb, const float* __restrict__ eemb,
                         float* __restrict__ wq_eff, float* __restrict__ wk_eff,
                         float* __restrict__ ev, float* __restrict__ vemb,
                         float* __restrict__ a_et, float* __restrict__ aqt,
                         float* __restrict__ akt, float* __restrict__ WvT) {
  int t = threadIdx.x;
  {
    int h = t >> 7, d = t & 127;
    float sq = 0.f, sk = 0.f;
    for (int c = 0; c < NC; ++c) {
      sq += att_i[h * NC + c] * Wq[(h * NC + c) * D + d];
      sk += att_j[h * NC + c] * Wk[(h * NC + c) * D + d];
    }
    wq_eff[t] = sq; wk_eff[t] = sk;
  }
  for (int i = t; i < D * D; i += 512) {
    int o = i >> 7, d = i & 127;
    WvT[d * D + o] = Wv[i];
  }
  __syncthreads();
  {
    int o = t & 127, tyg = t >> 7;
    for (int ty = tyg; ty < 8; ty += 4) {
      float se = 0.f, sn = 0.f;
      for (int dd = 0; dd < D; ++dd) {
        float w = WvT[dd * D + o];
        se = fmaf(w, eemb[ty * D + dd], se);
        sn = fmaf(w, nemb[ty * D + dd], sn);
      }
      ev[ty * D + o] = se; vemb[ty * D + o] = sn;
    }
  }
  if (t < 32) {
    int ty = t >> 2, hh = t & 3;
    float se = 0.f, sq2 = 0.f, sk2 = 0.f;
    for (int dd = 0; dd < D; ++dd) {
      se  += wk_eff[hh * D + dd] * eemb[ty * D + dd];
      sq2 += wq_eff[hh * D + dd] * nemb[ty * D + dd];
      sk2 += wk_eff[hh * D + dd] * nemb[ty * D + dd];
    }
    a_et[t] = se; aqt[t] = sq2; akt[t] = sk2;
  }
}

// ---------------- CSR build ----------------
__global__ void k_initcnt(int* __restrict__ counts) {
  int i = blockIdx.x * blockDim.x + threadIdx.x;
  if (i < NN) counts[i] = 1;  // self-loop
}

__global__ void k_hist(const int* __restrict__ ei, int* __restrict__ counts) {
  int e = blockIdx.x * blockDim.x + threadIdx.x;
  if (e < NE) atomicAdd(&counts[ei[NE + e]], 1);
}

__global__ __launch_bounds__(1024) void k_scan(const int* __restrict__ counts,
                                               int* __restrict__ rowptr,
                                               int* __restrict__ cursor) {
  __shared__ int sdata[1024];
  int t = threadIdx.x;
  int base = t * 40;
  int total = 0;
  int local[40];
#pragma unroll
  for (int j = 0; j < 40; ++j) {
    int idx = base + j;
    int c = (idx < NN) ? counts[idx] : 0;
    local[j] = total;
    total += c;
  }
  sdata[t] = total;
  for (int off = 1; off < 1024; off <<= 1) {
    __syncthreads();
    int v = (t >= off) ? sdata[t - off] : 0;
    __syncthreads();
    sdata[t] += v;
  }
  __syncthreads();
  int offset = sdata[t] - total;
#pragma unroll
  for (int j = 0; j < 40; ++j) {
    int idx = base + j;
    if (idx < NN) {
      int r = offset + local[j];
      rowptr[idx] = r;
      cursor[idx] = r;
    }
  }
  if (base <= NN - 1 && base + 40 >= NN) rowptr[NN] = offset + total;
}

__global__ void k_scatter(const int* __restrict__ ei, const int* __restrict__ etype,
                          int* __restrict__ cursor, unsigned* __restrict__ packed) {
  int i = blockIdx.x * blockDim.x + threadIdx.x;
  if (i >= NTOT) return;
  int dst; unsigned rec;
  if (i < NE) {
    dst = ei[NE + i];
    rec = (unsigned)ei[i] | ((unsigned)etype[i] << 16);
  } else {
    dst = i - NE;
    rec = (unsigned)dst;  // EDGE_TYPE_SELF = 0
  }
  int pos = atomicAdd(&cursor[dst], 1);
  packed[pos] = rec;
}

// ---------------- V projection as register-tiled GEMM ----------------
// Block 256 = 16 chgroups (8 ch each) x 16 nslots (4 nodes each) -> 128ch x 64 nodes.
// Wv^T in 64KiB LDS, XOR-swizzled at float4 granularity: row d (pitch 128 floats),
// float4 group g stored at (g ^ (d&31)). Staging writes conflict-free-ish, k-loop
// reads conflict-free and 16B-aligned. x streamed from global (L1-dedup'd).
__global__ __launch_bounds__(256) void k_xv(const float* __restrict__ x,
        const int* __restrict__ node_type, const float* __restrict__ Wv,
        const float* __restrict__ vemb, float* __restrict__ xv) {
  __shared__ float wsm[D * D];  // 64 KiB exactly
  int t = threadIdx.x;
  for (int idx = t; idx < D * D; idx += 256) {
    int o = idx >> 7, d = idx & 127;
    int g = o >> 2;
    wsm[(d << 7) | (((g ^ (d & 31)) << 2) | (o & 3))] = Wv[idx];
  }
  __syncthreads();
  int nslot = t & 15, chgroup = t >> 4;
  int o0 = chgroup * 8;
  int g0 = o0 >> 2;  // even
  int n0 = blockIdx.x * 64 + nslot * 4;  // 40000 = 625*64 exactly
  const float4* __restrict__ xr0 = (const float4*)(x + (size_t)(n0 + 0) * D);
  const float4* __restrict__ xr1 = (const float4*)(x + (size_t)(n0 + 1) * D);
  const float4* __restrict__ xr2 = (const float4*)(x + (size_t)(n0 + 2) * D);
  const float4* __restrict__ xr3 = (const float4*)(x + (size_t)(n0 + 3) * D);
  float4 a0[4], a1[4];
#pragma unroll
  for (int i = 0; i < 4; ++i) {
    a0[i] = make_float4(0.f, 0.f, 0.f, 0.f);
    a1[i] = make_float4(0.f, 0.f, 0.f, 0.f);
  }
#pragma unroll 2
  for (int kk = 0; kk < 32; ++kk) {
    float4 xx[4];
    xx[0] = xr0[kk]; xx[1] = xr1[kk]; xx[2] = xr2[kk]; xx[3] = xr3[kk];
#pragma unroll
    for (int j = 0; j < 4; ++j) {
      int d = 4 * kk + j;
      int dm = d & 31;
      const float4 w0 = *(const float4*)&wsm[(d << 7) | ((g0 ^ dm) << 2)];
      const float4 w1 = *(const float4*)&wsm[(d << 7) | (((g0 + 1) ^ dm) << 2)];
#pragma unroll
      for (int i = 0; i < 4; ++i) {
        float s = ((const float*)&xx[i])[j];
        a0[i].x = fmaf(w0.x, s, a0[i].x);
        a0[i].y = fmaf(w0.y, s, a0[i].y);
        a0[i].z = fmaf(w0.z, s, a0[i].z);
        a0[i].w = fmaf(w0.w, s, a0[i].w);
        a1[i].x = fmaf(w1.x, s, a1[i].x);
        a1[i].y = fmaf(w1.y, s, a1[i].y);
        a1[i].z = fmaf(w1.z, s, a1[i].z);
        a1[i].w = fmaf(w1.w, s, a1[i].w);
      }
    }
  }
#pragma unroll
  for (int i = 0; i < 4; ++i) {
    int n = n0 + i;
    int nt = node_type[n];
    const float4* __restrict__ vr = (const float4*)(vemb + nt * D + o0);
    float4 v0 = vr[0], v1 = vr[1];
    float4* __restrict__ outp = (float4*)(xv + (size_t)n * D + o0);
    outp[0] = make_float4(a0[i].x + v0.x, a0[i].y + v0.y, a0[i].z + v0.z, a0[i].w + v0.w);
    outp[1] = make_float4(a1[i].x + v1.x, a1[i].y + v1.y, a1[i].z + v1.z, a1[i].w + v1.w);
  }
}

// ---------------- aq/ak: one wave per node, butterfly reduce ----------------
__global__ __launch_bounds__(256) void k_aqak(const float* __restrict__ x,
        const int* __restrict__ node_type,
        const float* __restrict__ wq_eff, const float* __restrict__ wk_eff,
        const float* __restrict__ aqt, const float* __restrict__ akt,
        float* __restrict__ aq, float* __restrict__ ak) {
  int wid = (int)((blockIdx.x * blockDim.x + threadIdx.x) >> 6);
  int l = threadIdx.x & 63;
  if (wid >= NN) return;
  const float* __restrict__ xr = x + (size_t)wid * D;
  float x0 = xr[l], x1 = xr[l + 64];
  float p[8];
#pragma unroll
  for (int j = 0; j < 8; ++j) {
    const float* __restrict__ wrow = (j < 4) ? (wq_eff + j * D) : (wk_eff + (j - 4) * D);
    p[j] = wrow[l] * x0 + wrow[l + 64] * x1;
  }
#pragma unroll
  for (int j = 0; j < 8; ++j) {
#pragma unroll
    for (int off = 32; off >= 1; off >>= 1) p[j] += __shfl_xor(p[j], off, 64);
  }
  if (l == 0) {
    int nt = node_type[wid];
#pragma unroll
    for (int h = 0; h < NH; ++h) {
      aq[wid * NH + h] = p[h]     + aqt[nt * NH + h];
      ak[wid * NH + h] = p[4 + h] + akt[nt * NH + h];
    }
  }
}

// ---------------- gather: one wave per dst node, 1-deep prefetch pipeline ----
__global__ __launch_bounds__(256) void k_gather(const int* __restrict__ rowptr,
        const unsigned* __restrict__ packed,
        const float* __restrict__ aq, const float* __restrict__ ak,
        const float* __restrict__ a_et, const float* __restrict__ xv,
        const float* __restrict__ ev, const float* __restrict__ bias,
        float* __restrict__ out) {
  int n = (int)((blockIdx.x * blockDim.x + threadIdx.x) >> 6);
  int l = threadIdx.x & 63;
  if (n >= NN) return;
  int h = l >> 4;
  float aqh = aq[n * NH + h];
  int e0 = rowptr[n], e1 = rowptr[n + 1];
  const float2* __restrict__ xv2 = (const float2*)xv;
  const float2* __restrict__ ev2 = (const float2*)ev;
  float ax = 0.f, ay = 0.f, dsum = 0.f;
  // stage 0: prime
  unsigned rec = packed[e0];
  int src = (int)(rec & 0xFFFFu);
  int et  = (int)(rec >> 16);
  float sA = ak[src * NH + h] + a_et[et * NH + h];
  float2 v  = xv2[src * 64 + l];
  float2 ee = ev2[et * 64 + l];
  for (int e = e0 + 1; e <= e1; ++e) {
    float sA2; float2 v2, ee2;
    bool more = (e < e1);
    if (more) {
      unsigned rec2 = packed[e];
      int src2 = (int)(rec2 & 0xFFFFu);
      int et2  = (int)(rec2 >> 16);
      sA2 = ak[src2 * NH + h] + a_et[et2 * NH + h];
      v2  = xv2[src2 * 64 + l];
      ee2 = ev2[et2 * 64 + l];
    }
    float s = aqh + sA;
    s = (s > 0.f) ? s : NEG * s;
    float p = __expf(s);
    ax = fmaf(p, v.x + ee.x, ax);
    ay = fmaf(p, v.y + ee.y, ay);
    dsum += p;
    if (more) { sA = sA2; v = v2; ee = ee2; }
  }
  float inv = 1.f / (dsum + 1e-16f);
  out[(size_t)n * D + 2 * l]     = ax * inv + bias[2 * l];
  out[(size_t)n * D + 2 * l + 1] = ay * inv + bias[2 * l + 1];
}

extern "C" void kernel_launch(void* const* d_in, const int* in_sizes, int n_in,
                              void* d_out, int out_size, void* d_ws, size_t ws_size,
                              hipStream_t stream) {
  const float* x      = (const float*)d_in[0];
  const int*   ei     = (const int*)d_in[1];
  const int*   ntype  = (const int*)d_in[2];
  const int*   etype  = (const int*)d_in[3];
  const float* Wq     = (const float*)d_in[4];
  const float* Wk     = (const float*)d_in[5];
  const float* Wv     = (const float*)d_in[6];
  const float* att_i  = (const float*)d_in[7];
  const float* att_j  = (const float*)d_in[8];
  const float* bias   = (const float*)d_in[9];
  const float* nemb   = (const float*)d_in[10];
  const float* eemb   = (const float*)d_in[11];
  float* out = (float*)d_out;

  float* ws     = (float*)d_ws;
  float* xv     = ws;                         // NN*128
  float* aq     = xv + (size_t)NN * D;        // NN*4
  float* ak     = aq + NN * NH;               // NN*4
  float* wq_eff = ak + NN * NH;               // 512
  float* wk_eff = wq_eff + 512;               // 512
  float* ev     = wk_eff + 512;               // 1024
  float* vemb   = ev + 1024;                  // 1024
  float* a_et   = vemb + 1024;                // 32
  float* aqt    = a_et + 32;                  // 32
  float* akt    = aqt + 32;                   // 32
  float* WvT    = akt + 32;                   // 16384
  int*   counts = (int*)(WvT + D * D);        // NN
  int*   rowptr = counts + NN;                // NN+1
  int*   cursor = rowptr + NN + 1;            // NN
  unsigned* packed = (unsigned*)(cursor + NN);// NTOT

  k_consts<<<dim3(1), dim3(512), 0, stream>>>(Wq, Wk, Wv, att_i, att_j, nemb, eemb,
                                              wq_eff, wk_eff, ev, vemb, a_et, aqt, akt, WvT);
  k_initcnt<<<dim3((NN + 255) / 256), dim3(256), 0, stream>>>(counts);
  k_hist<<<dim3((NE + 255) / 256), dim3(256), 0, stream>>>(ei, counts);
  k_scan<<<dim3(1), dim3(1024), 0, stream>>>(counts, rowptr, cursor);
  k_scatter<<<dim3((NTOT + 255) / 256), dim3(256), 0, stream>>>(ei, etype, cursor, packed);
  k_xv<<<dim3(625), dim3(256), 0, stream>>>(x, ntype, Wv, vemb, xv);
  k_aqak<<<dim3((NN + 3) / 4), dim3(256), 0, stream>>>(x, ntype, wq_eff, wk_eff, aqt, akt, aq, ak);
  k_gather<<<dim3((NN + 3) / 4), dim3(256), 0, stream>>>(rowptr, packed, aq, ak, a_et, xv, ev, bias, out);
}

// Round 5
// 326.767 us; speedup vs baseline: 2.6664x; 1.2667x over previous
//
#include <hip/hip_runtime.h>
#include <math.h>

#define NN 40000
#define NE 640000
#define NTOT (NE + NN)
#define D 128
#define NH 4
#define NC 32
#define NEG 0.2f

__device__ __forceinline__ unsigned pack_bf16(float a, float b) {
  unsigned ua = __float_as_uint(a), ub = __float_as_uint(b);
  ua = (ua + 0x7FFFu + ((ua >> 16) & 1u)) >> 16;
  ub = (ub + 0x7FFFu + ((ub >> 16) & 1u)) & 0xFFFF0000u;
  return ub | ua;
}

// ---------------- per-type constants (1 block, 512 threads) ----------------
__global__ void k_consts(const float* __restrict__ Wq, const float* __restrict__ Wk,
                         const float* __restrict__ Wv, const float* __restrict__ att_i,
                         const float* __restrict__ att_j,
                         const float* __restrict__ nemb, const float* __restrict__ eemb,
                         float* __restrict__ wq_eff, float* __restrict__ wk_eff,
                         float* __restrict__ ev, float* __restrict__ vemb,
                         float* __restrict__ a_et, float* __restrict__ aqt,
                         float* __restrict__ akt, float* __restrict__ WvT) {
  int t = threadIdx.x;
  {
    int h = t >> 7, d = t & 127;
    float sq = 0.f, sk = 0.f;
    for (int c = 0; c < NC; ++c) {
      sq += att_i[h * NC + c] * Wq[(h * NC + c) * D + d];
      sk += att_j[h * NC + c] * Wk[(h * NC + c) * D + d];
    }
    wq_eff[t] = sq; wk_eff[t] = sk;
  }
  for (int i = t; i < D * D; i += 512) {
    int o = i >> 7, d = i & 127;
    WvT[d * D + o] = Wv[i];
  }
  __syncthreads();
  {
    int o = t & 127, tyg = t >> 7;
    for (int ty = tyg; ty < 8; ty += 4) {
      float se = 0.f, sn = 0.f;
      for (int dd = 0; dd < D; ++dd) {
        float w = WvT[dd * D + o];
        se = fmaf(w, eemb[ty * D + dd], se);
        sn = fmaf(w, nemb[ty * D + dd], sn);
      }
      ev[ty * D + o] = se; vemb[ty * D + o] = sn;
    }
  }
  if (t < 32) {
    int ty = t >> 2, hh = t & 3;
    float se = 0.f, sq2 = 0.f, sk2 = 0.f;
    for (int dd = 0; dd < D; ++dd) {
      se  += wk_eff[hh * D + dd] * eemb[ty * D + dd];
      sq2 += wq_eff[hh * D + dd] * nemb[ty * D + dd];
      sk2 += wk_eff[hh * D + dd] * nemb[ty * D + dd];
    }
    a_et[t] = se; aqt[t] = sq2; akt[t] = sk2;
  }
}

// ---------------- CSR build ----------------
__global__ void k_hist(const int* __restrict__ ei, int* __restrict__ counts) {
  int i = blockIdx.x * blockDim.x + threadIdx.x;
  if (i >= NE / 4) return;
  int4 d4 = ((const int4*)(ei + NE))[i];
  atomicAdd(&counts[d4.x], 1);
  atomicAdd(&counts[d4.y], 1);
  atomicAdd(&counts[d4.z], 1);
  atomicAdd(&counts[d4.w], 1);
}

__global__ __launch_bounds__(1024) void k_scan(const int* __restrict__ counts,
                                               int* __restrict__ rowptr,
                                               int* __restrict__ cursor) {
  __shared__ int sdata[1024];
  int t = threadIdx.x;
  int total = 0;
  int local[40];
  if (t < 1000) {
    const int* __restrict__ cp = counts + t * 40;
#pragma unroll
    for (int j = 0; j < 40; ++j) {
      local[j] = total;
      total += cp[j] + 1;  // +1 self-loop
    }
  }
  sdata[t] = total;
  for (int off = 1; off < 1024; off <<= 1) {
    __syncthreads();
    int v = (t >= off) ? sdata[t - off] : 0;
    __syncthreads();
    sdata[t] += v;
  }
  __syncthreads();
  int offset = sdata[t] - total;
  if (t < 1000) {
    int base = t * 40;
#pragma unroll
    for (int j = 0; j < 40; ++j) {
      int r = offset + local[j];
      rowptr[base + j] = r;
      cursor[base + j] = r;
    }
    if (t == 999) rowptr[NN] = offset + total;  // = NTOT
  }
}

__global__ void k_scatter(const int* __restrict__ ei, const int* __restrict__ etype,
                          int* __restrict__ cursor, unsigned* __restrict__ packed) {
  int i = blockIdx.x * blockDim.x + threadIdx.x;
  if (i < NE / 4) {
    int4 s4 = ((const int4*)ei)[i];
    int4 d4 = ((const int4*)(ei + NE))[i];
    int4 t4 = ((const int4*)etype)[i];
    int pos;
    pos = atomicAdd(&cursor[d4.x], 1); packed[pos] = (unsigned)s4.x | ((unsigned)t4.x << 16);
    pos = atomicAdd(&cursor[d4.y], 1); packed[pos] = (unsigned)s4.y | ((unsigned)t4.y << 16);
    pos = atomicAdd(&cursor[d4.z], 1); packed[pos] = (unsigned)s4.z | ((unsigned)t4.z << 16);
    pos = atomicAdd(&cursor[d4.w], 1); packed[pos] = (unsigned)s4.w | ((unsigned)t4.w << 16);
  } else if (i < NE / 4 + NN) {
    int n = i - NE / 4;
    int pos = atomicAdd(&cursor[n], 1);
    packed[pos] = (unsigned)n;  // EDGE_TYPE_SELF = 0
  }
}

// ---------------- V projection GEMM (bf16 output) + fused aq/ak ----------------
__global__ __launch_bounds__(256) void k_xv(const float* __restrict__ x,
        const int* __restrict__ node_type, const float* __restrict__ Wv,
        const float* __restrict__ vemb, unsigned* __restrict__ xvh,
        const float* __restrict__ wq_eff, const float* __restrict__ wk_eff,
        const float* __restrict__ aqt, const float* __restrict__ akt,
        float* __restrict__ aq, float* __restrict__ ak) {
  __shared__ float wsm[D * D];  // 64 KiB
  int t = threadIdx.x;
  for (int idx = t; idx < D * D; idx += 256) {
    int o = idx >> 7, d = idx & 127;
    int g = o >> 2;
    wsm[(d << 7) | (((g ^ (d & 31)) << 2) | (o & 3))] = Wv[idx];
  }
  __syncthreads();
  int nslot = t & 15, chgroup = t >> 4;
  int o0 = chgroup * 8;
  int g0 = o0 >> 2;
  int n0 = blockIdx.x * 64 + nslot * 4;  // 40000 = 625*64
  const float4* __restrict__ xr0 = (const float4*)(x + (size_t)(n0 + 0) * D);
  const float4* __restrict__ xr1 = (const float4*)(x + (size_t)(n0 + 1) * D);
  const float4* __restrict__ xr2 = (const float4*)(x + (size_t)(n0 + 2) * D);
  const float4* __restrict__ xr3 = (const float4*)(x + (size_t)(n0 + 3) * D);
  float4 a0[4], a1[4];
#pragma unroll
  for (int i = 0; i < 4; ++i) {
    a0[i] = make_float4(0.f, 0.f, 0.f, 0.f);
    a1[i] = make_float4(0.f, 0.f, 0.f, 0.f);
  }
#pragma unroll 2
  for (int kk = 0; kk < 32; ++kk) {
    float4 xx[4];
    xx[0] = xr0[kk]; xx[1] = xr1[kk]; xx[2] = xr2[kk]; xx[3] = xr3[kk];
#pragma unroll
    for (int j = 0; j < 4; ++j) {
      int d = 4 * kk + j;
      int dm = d & 31;
      const float4 w0 = *(const float4*)&wsm[(d << 7) | ((g0 ^ dm) << 2)];
      const float4 w1 = *(const float4*)&wsm[(d << 7) | (((g0 + 1) ^ dm) << 2)];
#pragma unroll
      for (int i = 0; i < 4; ++i) {
        float s = ((const float*)&xx[i])[j];
        a0[i].x = fmaf(w0.x, s, a0[i].x);
        a0[i].y = fmaf(w0.y, s, a0[i].y);
        a0[i].z = fmaf(w0.z, s, a0[i].z);
        a0[i].w = fmaf(w0.w, s, a0[i].w);
        a1[i].x = fmaf(w1.x, s, a1[i].x);
        a1[i].y = fmaf(w1.y, s, a1[i].y);
        a1[i].z = fmaf(w1.z, s, a1[i].z);
        a1[i].w = fmaf(w1.w, s, a1[i].w);
      }
    }
  }
#pragma unroll
  for (int i = 0; i < 4; ++i) {
    int n = n0 + i;
    int nt = node_type[n];
    const float4* __restrict__ vr = (const float4*)(vemb + nt * D + o0);
    float4 v0 = vr[0], v1 = vr[1];
    uint4 pk;
    pk.x = pack_bf16(a0[i].x + v0.x, a0[i].y + v0.y);
    pk.y = pack_bf16(a0[i].z + v0.z, a0[i].w + v0.w);
    pk.z = pack_bf16(a1[i].x + v1.x, a1[i].y + v1.y);
    pk.w = pack_bf16(a1[i].z + v1.z, a1[i].w + v1.w);
    ((uint4*)xvh)[n * 16 + chgroup] = pk;  // row = 64 uints = 16 uint4 (R4 bug: was n*8)
  }
  // ---- fused aq/ak: 512 tasks = 64 nodes x 8 rows (4 wq + 4 wk) ----
  for (int idx = t; idx < 512; idx += 256) {
    int nl = idx >> 3, j = idx & 7;
    int n = blockIdx.x * 64 + nl;
    const float4* __restrict__ xr = (const float4*)(x + (size_t)n * D);
    const float4* __restrict__ wr = (const float4*)((j < 4) ? (wq_eff + j * D)
                                                            : (wk_eff + (j - 4) * D));
    float4 s4 = make_float4(0.f, 0.f, 0.f, 0.f);
#pragma unroll
    for (int k = 0; k < 32; ++k) {
      float4 xx = xr[k], ww = wr[k];
      s4.x = fmaf(xx.x, ww.x, s4.x);
      s4.y = fmaf(xx.y, ww.y, s4.y);
      s4.z = fmaf(xx.z, ww.z, s4.z);
      s4.w = fmaf(xx.w, ww.w, s4.w);
    }
    float s = (s4.x + s4.y) + (s4.z + s4.w);
    int nt = node_type[n];
    if (j < 4) aq[n * NH + j] = s + aqt[nt * NH + j];
    else       ak[n * NH + (j - 4)] = s + akt[nt * NH + (j - 4)];
  }
}

// ---------------- gather: one wave per dst, split-wave dual-edge, bf16 xv ----
__global__ __launch_bounds__(256) void k_gather(const int* __restrict__ rowptr,
        const unsigned* __restrict__ packed,
        const float* __restrict__ aq, const float* __restrict__ ak,
        const float* __restrict__ a_et, const unsigned* __restrict__ xvh,
        const float* __restrict__ ev, const float* __restrict__ bias,
        float* __restrict__ out) {
  int n = (int)((blockIdx.x * blockDim.x + threadIdx.x) >> 6);
  int l = threadIdx.x & 63;
  if (n >= NN) return;
  int q = l & 31, half = l >> 5;
  int h = q >> 3;
  float aqh = aq[n * NH + h];
  int e0 = rowptr[n], e1 = rowptr[n + 1];
  const uint2* __restrict__ xv2 = (const uint2*)xvh;   // row = 32 uint2
  const float4* __restrict__ ev4 = (const float4*)ev;  // row = 32 float4
  float acc0 = 0.f, acc1 = 0.f, acc2 = 0.f, acc3 = 0.f, dsum = 0.f;
  int deg = e1 - e0;
  int iters = (deg + 1) >> 1;
  int e = e0 + half;
  bool val = (e < e1);
  {
    unsigned rec = packed[val ? e : e0];
    int src = (int)(rec & 0xFFFFu), et = (int)(rec >> 16);
    float sA = ak[src * NH + h] + a_et[et * NH + h];
    uint2 vb = xv2[src * 32 + q];
    float4 ew = ev4[et * 32 + q];
    for (int it = 0; it < iters; ++it) {
      int e2 = e + 2;
      bool v2 = (e2 < e1);
      float sA2 = 0.f; uint2 vb2 = make_uint2(0, 0);
      float4 ew2 = make_float4(0.f, 0.f, 0.f, 0.f);
      if (it + 1 < iters) {  // wave-uniform
        unsigned rec2 = packed[v2 ? e2 : e0];
        int src2 = (int)(rec2 & 0xFFFFu), et2 = (int)(rec2 >> 16);
        sA2 = ak[src2 * NH + h] + a_et[et2 * NH + h];
        vb2 = xv2[src2 * 32 + q];
        ew2 = ev4[et2 * 32 + q];
      }
      float s = aqh + sA;
      s = (s > 0.f) ? s : NEG * s;
      float p = val ? __expf(s) : 0.f;
      float f0 = __uint_as_float(vb.x << 16);
      float f1 = __uint_as_float(vb.x & 0xFFFF0000u);
      float f2 = __uint_as_float(vb.y << 16);
      float f3 = __uint_as_float(vb.y & 0xFFFF0000u);
      acc0 = fmaf(p, f0 + ew.x, acc0);
      acc1 = fmaf(p, f1 + ew.y, acc1);
      acc2 = fmaf(p, f2 + ew.z, acc2);
      acc3 = fmaf(p, f3 + ew.w, acc3);
      dsum += p;
      e = e2; val = v2; sA = sA2; vb = vb2; ew = ew2;
    }
  }
  acc0 += __shfl_xor(acc0, 32);
  acc1 += __shfl_xor(acc1, 32);
  acc2 += __shfl_xor(acc2, 32);
  acc3 += __shfl_xor(acc3, 32);
  dsum += __shfl_xor(dsum, 32);
  if (half == 0) {
    float inv = 1.f / (dsum + 1e-16f);
    const float4 b4 = *(const float4*)(bias + 4 * q);
    float4 o;
    o.x = acc0 * inv + b4.x;
    o.y = acc1 * inv + b4.y;
    o.z = acc2 * inv + b4.z;
    o.w = acc3 * inv + b4.w;
    *((float4*)(out + (size_t)n * D + 4 * q)) = o;
  }
}

extern "C" void kernel_launch(void* const* d_in, const int* in_sizes, int n_in,
                              void* d_out, int out_size, void* d_ws, size_t ws_size,
                              hipStream_t stream) {
  const float* x      = (const float*)d_in[0];
  const int*   ei     = (const int*)d_in[1];
  const int*   ntype  = (const int*)d_in[2];
  const int*   etype  = (const int*)d_in[3];
  const float* Wq     = (const float*)d_in[4];
  const float* Wk     = (const float*)d_in[5];
  const float* Wv     = (const float*)d_in[6];
  const float* att_i  = (const float*)d_in[7];
  const float* att_j  = (const float*)d_in[8];
  const float* bias   = (const float*)d_in[9];
  const float* nemb   = (const float*)d_in[10];
  const float* eemb   = (const float*)d_in[11];
  float* out = (float*)d_out;

  float* ws     = (float*)d_ws;
  unsigned* xvh = (unsigned*)ws;              // NN*64 uints (bf16 pairs)
  float* aq     = ws + (size_t)NN * 64;       // NN*4
  float* ak     = aq + NN * NH;               // NN*4
  float* wq_eff = ak + NN * NH;               // 512
  float* wk_eff = wq_eff + 512;               // 512
  float* ev     = wk_eff + 512;               // 1024
  float* vemb   = ev + 1024;                  // 1024
  float* a_et   = vemb + 1024;                // 32
  float* aqt    = a_et + 32;                  // 32
  float* akt    = aqt + 32;                   // 32
  float* WvT    = akt + 32;                   // 16384
  int*   counts = (int*)(WvT + D * D);        // NN
  int*   rowptr = counts + NN;                // NN+1
  int*   cursor = rowptr + NN + 1;            // NN
  unsigned* packed = (unsigned*)(cursor + NN);// NTOT

  hipMemsetAsync(counts, 0, NN * sizeof(int), stream);
  k_consts<<<dim3(1), dim3(512), 0, stream>>>(Wq, Wk, Wv, att_i, att_j, nemb, eemb,
                                              wq_eff, wk_eff, ev, vemb, a_et, aqt, akt, WvT);
  k_hist<<<dim3((NE / 4 + 255) / 256), dim3(256), 0, stream>>>(ei, counts);
  k_scan<<<dim3(1), dim3(1024), 0, stream>>>(counts, rowptr, cursor);
  k_scatter<<<dim3((NE / 4 + NN + 255) / 256), dim3(256), 0, stream>>>(ei, etype, cursor, packed);
  k_xv<<<dim3(625), dim3(256), 0, stream>>>(x, ntype, Wv, vemb, xvh,
                                            wq_eff, wk_eff, aqt, akt, aq, ak);
  k_gather<<<dim3((NN + 3) / 4), dim3(256), 0, stream>>>(rowptr, packed, aq, ak, a_et,
                                                         xvh, ev, bias, out);
}

// Round 6
// 288.904 us; speedup vs baseline: 3.0159x; 1.1311x over previous
//
#include <hip/hip_runtime.h>
#include <math.h>

#define NN 40000
#define NE 640000
#define NTOT (NE + NN)
#define D 128
#define NH 4
#define NC 32
#define NEG 0.2f

typedef __attribute__((ext_vector_type(8))) short bf16x8;
typedef __attribute__((ext_vector_type(4))) float f32x4;

__device__ __forceinline__ unsigned pack_bf16(float a, float b) {
  unsigned ua = __float_as_uint(a), ub = __float_as_uint(b);
  ua = (ua + 0x7FFFu + ((ua >> 16) & 1u)) >> 16;
  ub = (ub + 0x7FFFu + ((ub >> 16) & 1u)) & 0xFFFF0000u;
  return ub | ua;
}

__device__ __forceinline__ bf16x8 to_bf16x8(float4 a, float4 b) {
  union { bf16x8 v; unsigned u[4]; } r;
  r.u[0] = pack_bf16(a.x, a.y);
  r.u[1] = pack_bf16(a.z, a.w);
  r.u[2] = pack_bf16(b.x, b.y);
  r.u[3] = pack_bf16(b.z, b.w);
  return r.v;
}

// ---------------- per-type constants (1 block, 512 threads) ----------------
__global__ void k_consts(const float* __restrict__ Wq, const float* __restrict__ Wk,
                         const float* __restrict__ Wv, const float* __restrict__ att_i,
                         const float* __restrict__ att_j,
                         const float* __restrict__ nemb, const float* __restrict__ eemb,
                         float* __restrict__ wq_eff, float* __restrict__ wk_eff,
                         float* __restrict__ weff16,
                         float* __restrict__ ev, float* __restrict__ vemb,
                         float* __restrict__ a_et, float* __restrict__ aqt,
                         float* __restrict__ akt, float* __restrict__ WvT) {
  int t = threadIdx.x;
  {
    int h = t >> 7, d = t & 127;
    float sq = 0.f, sk = 0.f;
    for (int c = 0; c < NC; ++c) {
      sq += att_i[h * NC + c] * Wq[(h * NC + c) * D + d];
      sk += att_j[h * NC + c] * Wk[(h * NC + c) * D + d];
    }
    wq_eff[t] = sq; wk_eff[t] = sk;
    weff16[t] = sq;          // rows 0..3  = wq_eff
    weff16[512 + t] = sk;    // rows 4..7  = wk_eff
    weff16[1024 + t] = 0.f;  // rows 8..15 = zero pad
    weff16[1536 + t] = 0.f;
  }
  for (int i = t; i < D * D; i += 512) {
    int o = i >> 7, d = i & 127;
    WvT[d * D + o] = Wv[i];
  }
  __syncthreads();
  {
    int o = t & 127, tyg = t >> 7;
    for (int ty = tyg; ty < 8; ty += 4) {
      float se = 0.f, sn = 0.f;
      for (int dd = 0; dd < D; ++dd) {
        float w = WvT[dd * D + o];
        se = fmaf(w, eemb[ty * D + dd], se);
        sn = fmaf(w, nemb[ty * D + dd], sn);
      }
      ev[ty * D + o] = se; vemb[ty * D + o] = sn;
    }
  }
  if (t < 32) {
    int ty = t >> 2, hh = t & 3;
    float se = 0.f, sq2 = 0.f, sk2 = 0.f;
    for (int dd = 0; dd < D; ++dd) {
      se  += wk_eff[hh * D + dd] * eemb[ty * D + dd];
      sq2 += wq_eff[hh * D + dd] * nemb[ty * D + dd];
      sk2 += wk_eff[hh * D + dd] * nemb[ty * D + dd];
    }
    a_et[t] = se; aqt[t] = sq2; akt[t] = sk2;
  }
}

// ---------------- CSR build ----------------
__global__ void k_hist(const int* __restrict__ ei, int* __restrict__ counts) {
  int i = blockIdx.x * blockDim.x + threadIdx.x;
  if (i >= NE / 4) return;
  int4 d4 = ((const int4*)(ei + NE))[i];
  atomicAdd(&counts[d4.x], 1);
  atomicAdd(&counts[d4.y], 1);
  atomicAdd(&counts[d4.z], 1);
  atomicAdd(&counts[d4.w], 1);
}

__global__ __launch_bounds__(1024) void k_scan(const int* __restrict__ counts,
                                               int* __restrict__ rowptr,
                                               int* __restrict__ cursor) {
  __shared__ int sdata[1024];
  int t = threadIdx.x;
  int total = 0;
  int local[40];
  if (t < 1000) {
    const int* __restrict__ cp = counts + t * 40;
#pragma unroll
    for (int j = 0; j < 40; ++j) {
      local[j] = total;
      total += cp[j] + 1;  // +1 self-loop
    }
  }
  sdata[t] = total;
  for (int off = 1; off < 1024; off <<= 1) {
    __syncthreads();
    int v = (t >= off) ? sdata[t - off] : 0;
    __syncthreads();
    sdata[t] += v;
  }
  __syncthreads();
  int offset = sdata[t] - total;
  if (t < 1000) {
    int base = t * 40;
#pragma unroll
    for (int j = 0; j < 40; ++j) {
      int r = offset + local[j];
      rowptr[base + j] = r;
      cursor[base + j] = r;
    }
    if (t == 999) rowptr[NN] = offset + total;  // = NTOT
  }
}

__global__ void k_scatter(const int* __restrict__ ei, const int* __restrict__ etype,
                          int* __restrict__ cursor, unsigned* __restrict__ packed) {
  int i = blockIdx.x * blockDim.x + threadIdx.x;
  if (i < NE / 4) {
    int4 s4 = ((const int4*)ei)[i];
    int4 d4 = ((const int4*)(ei + NE))[i];
    int4 t4 = ((const int4*)etype)[i];
    int pos;
    pos = atomicAdd(&cursor[d4.x], 1); packed[pos] = (unsigned)s4.x | ((unsigned)t4.x << 16);
    pos = atomicAdd(&cursor[d4.y], 1); packed[pos] = (unsigned)s4.y | ((unsigned)t4.y << 16);
    pos = atomicAdd(&cursor[d4.z], 1); packed[pos] = (unsigned)s4.z | ((unsigned)t4.z << 16);
    pos = atomicAdd(&cursor[d4.w], 1); packed[pos] = (unsigned)s4.w | ((unsigned)t4.w << 16);
  } else if (i < NE / 4 + NN) {
    int n = i - NE / 4;
    int pos = atomicAdd(&cursor[n], 1);
    packed[pos] = (unsigned)n;  // EDGE_TYPE_SELF = 0
  }
}

// ---------------- V projection + aq/ak via MFMA (no LDS) ----------------
// Block = 4 waves; wave w owns 16 nodes. 9 channel-tiles of 16:
// tiles 0..7 = Wv channels (-> xvh bf16), tile 8 = [wq_eff;wk_eff;0-pad] (-> aq/ak).
// A frag: m=lane&15 (node), k=quad*8+j. B frag: n=lane&15 (channel row of Wv), same k.
// C/D: col=lane&15 (channel), row=quad*4+reg (node).
__global__ __launch_bounds__(256) void k_xv(const float* __restrict__ x,
        const int* __restrict__ node_type, const float* __restrict__ Wv,
        const float* __restrict__ weff16, const float* __restrict__ vemb,
        const float* __restrict__ aqt, const float* __restrict__ akt,
        unsigned* __restrict__ xvh, float* __restrict__ aq, float* __restrict__ ak) {
  int t = threadIdx.x;
  int w = t >> 6, l = t & 63;
  int quad = l >> 4, col = l & 15;
  int n0w = blockIdx.x * 64 + w * 16;  // 40000 = 625*64
  const float4* __restrict__ xr = (const float4*)(x + (size_t)(n0w + col) * D);
  bf16x8 afr[4];
#pragma unroll
  for (int s = 0; s < 4; ++s) {
    const float4* p = xr + s * 8 + quad * 2;
    afr[s] = to_bf16x8(p[0], p[1]);
  }
  f32x4 acc[9];
#pragma unroll
  for (int ct = 0; ct < 9; ++ct) acc[ct] = (f32x4){0.f, 0.f, 0.f, 0.f};
#pragma unroll
  for (int ct = 0; ct < 9; ++ct) {
    const float4* __restrict__ brow = (ct < 8)
        ? (const float4*)(Wv + (size_t)(ct * 16 + col) * D)
        : (const float4*)(weff16 + (size_t)col * D);
#pragma unroll
    for (int s = 0; s < 4; ++s) {
      const float4* p = brow + s * 8 + quad * 2;
      bf16x8 bfr = to_bf16x8(p[0], p[1]);
      acc[ct] = __builtin_amdgcn_mfma_f32_16x16x32_bf16(afr[s], bfr, acc[ct], 0, 0, 0);
    }
  }
  // epilogue
  int nodes[4]; int ntv[4];
#pragma unroll
  for (int r = 0; r < 4; ++r) {
    nodes[r] = n0w + quad * 4 + r;
    ntv[r] = node_type[nodes[r]];
  }
#pragma unroll
  for (int ct = 0; ct < 8; ++ct) {
    int c = ct * 16 + col;
#pragma unroll
    for (int r = 0; r < 4; ++r) {
      float val = acc[ct][r] + vemb[ntv[r] * D + c];
      float pv = __shfl_xor(val, 1);
      if (!(col & 1)) {
        xvh[nodes[r] * 64 + ct * 8 + (col >> 1)] = pack_bf16(val, pv);
      }
    }
  }
  if (col < 4) {
#pragma unroll
    for (int r = 0; r < 4; ++r)
      aq[nodes[r] * NH + col] = acc[8][r] + aqt[ntv[r] * NH + col];
  } else if (col < 8) {
#pragma unroll
    for (int r = 0; r < 4; ++r)
      ak[nodes[r] * NH + (col - 4)] = acc[8][r] + akt[ntv[r] * NH + (col - 4)];
  }
}

// ---------------- gather: one wave per dst, split-wave dual-edge, bf16 xv ----
__global__ __launch_bounds__(256) void k_gather(const int* __restrict__ rowptr,
        const unsigned* __restrict__ packed,
        const float* __restrict__ aq, const float* __restrict__ ak,
        const float* __restrict__ a_et, const unsigned* __restrict__ xvh,
        const float* __restrict__ ev, const float* __restrict__ bias,
        float* __restrict__ out) {
  int n = (int)((blockIdx.x * blockDim.x + threadIdx.x) >> 6);
  int l = threadIdx.x & 63;
  if (n >= NN) return;
  int q = l & 31, half = l >> 5;
  int h = q >> 3;
  float aqh = aq[n * NH + h];
  int e0 = rowptr[n], e1 = rowptr[n + 1];
  const uint2* __restrict__ xv2 = (const uint2*)xvh;   // row = 32 uint2
  const float4* __restrict__ ev4 = (const float4*)ev;  // row = 32 float4
  float acc0 = 0.f, acc1 = 0.f, acc2 = 0.f, acc3 = 0.f, dsum = 0.f;
  int deg = e1 - e0;
  int iters = (deg + 1) >> 1;
  int e = e0 + half;
  bool val = (e < e1);
  {
    unsigned rec = packed[val ? e : e0];
    int src = (int)(rec & 0xFFFFu), et = (int)(rec >> 16);
    float sA = ak[src * NH + h] + a_et[et * NH + h];
    uint2 vb = xv2[src * 32 + q];
    float4 ew = ev4[et * 32 + q];
    for (int it = 0; it < iters; ++it) {
      int e2 = e + 2;
      bool v2 = (e2 < e1);
      float sA2 = 0.f; uint2 vb2 = make_uint2(0, 0);
      float4 ew2 = make_float4(0.f, 0.f, 0.f, 0.f);
      if (it + 1 < iters) {  // wave-uniform
        unsigned rec2 = packed[v2 ? e2 : e0];
        int src2 = (int)(rec2 & 0xFFFFu), et2 = (int)(rec2 >> 16);
        sA2 = ak[src2 * NH + h] + a_et[et2 * NH + h];
        vb2 = xv2[src2 * 32 + q];
        ew2 = ev4[et2 * 32 + q];
      }
      float s = aqh + sA;
      s = (s > 0.f) ? s : NEG * s;
      float p = val ? __expf(s) : 0.f;
      float f0 = __uint_as_float(vb.x << 16);
      float f1 = __uint_as_float(vb.x & 0xFFFF0000u);
      float f2 = __uint_as_float(vb.y << 16);
      float f3 = __uint_as_float(vb.y & 0xFFFF0000u);
      acc0 = fmaf(p, f0 + ew.x, acc0);
      acc1 = fmaf(p, f1 + ew.y, acc1);
      acc2 = fmaf(p, f2 + ew.z, acc2);
      acc3 = fmaf(p, f3 + ew.w, acc3);
      dsum += p;
      e = e2; val = v2; sA = sA2; vb = vb2; ew = ew2;
    }
  }
  acc0 += __shfl_xor(acc0, 32);
  acc1 += __shfl_xor(acc1, 32);
  acc2 += __shfl_xor(acc2, 32);
  acc3 += __shfl_xor(acc3, 32);
  dsum += __shfl_xor(dsum, 32);
  if (half == 0) {
    float inv = 1.f / (dsum + 1e-16f);
    const float4 b4 = *(const float4*)(bias + 4 * q);
    float4 o;
    o.x = acc0 * inv + b4.x;
    o.y = acc1 * inv + b4.y;
    o.z = acc2 * inv + b4.z;
    o.w = acc3 * inv + b4.w;
    *((float4*)(out + (size_t)n * D + 4 * q)) = o;
  }
}

extern "C" void kernel_launch(void* const* d_in, const int* in_sizes, int n_in,
                              void* d_out, int out_size, void* d_ws, size_t ws_size,
                              hipStream_t stream) {
  const float* x      = (const float*)d_in[0];
  const int*   ei     = (const int*)d_in[1];
  const int*   ntype  = (const int*)d_in[2];
  const int*   etype  = (const int*)d_in[3];
  const float* Wq     = (const float*)d_in[4];
  const float* Wk     = (const float*)d_in[5];
  const float* Wv     = (const float*)d_in[6];
  const float* att_i  = (const float*)d_in[7];
  const float* att_j  = (const float*)d_in[8];
  const float* bias   = (const float*)d_in[9];
  const float* nemb   = (const float*)d_in[10];
  const float* eemb   = (const float*)d_in[11];
  float* out = (float*)d_out;

  float* ws     = (float*)d_ws;
  unsigned* xvh = (unsigned*)ws;              // NN*64 uints (bf16 pairs)
  float* aq     = ws + (size_t)NN * 64;       // NN*4
  float* ak     = aq + NN * NH;               // NN*4
  float* wq_eff = ak + NN * NH;               // 512
  float* wk_eff = wq_eff + 512;               // 512
  float* weff16 = wk_eff + 512;               // 2048 (16 rows x 128)
  float* ev     = weff16 + 2048;              // 1024
  float* vemb   = ev + 1024;                  // 1024
  float* a_et   = vemb + 1024;                // 32
  float* aqt    = a_et + 32;                  // 32
  float* akt    = aqt + 32;                   // 32
  float* WvT    = akt + 32;                   // 16384
  int*   counts = (int*)(WvT + D * D);        // NN
  int*   rowptr = counts + NN;                // NN+1
  int*   cursor = rowptr + NN + 1;            // NN
  unsigned* packed = (unsigned*)(cursor + NN);// NTOT

  hipMemsetAsync(counts, 0, NN * sizeof(int), stream);
  k_consts<<<dim3(1), dim3(512), 0, stream>>>(Wq, Wk, Wv, att_i, att_j, nemb, eemb,
                                              wq_eff, wk_eff, weff16, ev, vemb,
                                              a_et, aqt, akt, WvT);
  k_hist<<<dim3((NE / 4 + 255) / 256), dim3(256), 0, stream>>>(ei, counts);
  k_scan<<<dim3(1), dim3(1024), 0, stream>>>(counts, rowptr, cursor);
  k_scatter<<<dim3((NE / 4 + NN + 255) / 256), dim3(256), 0, stream>>>(ei, etype, cursor, packed);
  k_xv<<<dim3(625), dim3(256), 0, stream>>>(x, ntype, Wv, weff16, vemb, aqt, akt,
                                            xvh, aq, ak);
  k_gather<<<dim3((NN + 3) / 4), dim3(256), 0, stream>>>(rowptr, packed, aq, ak, a_et,
                                                         xvh, ev, bias, out);
}

// Round 7
// 205.797 us; speedup vs baseline: 4.2338x; 1.4038x over previous
//
#include <hip/hip_runtime.h>
#include <math.h>

#define NN 40000
#define NE 640000
#define NTOT (NE + NN)
#define D 128
#define NH 4
#define NC 32
#define NEG 0.2f

typedef __attribute__((ext_vector_type(8))) short bf16x8;
typedef __attribute__((ext_vector_type(4))) float f32x4;

__device__ __forceinline__ unsigned pack_bf16(float a, float b) {
  unsigned ua = __float_as_uint(a), ub = __float_as_uint(b);
  ua = (ua + 0x7FFFu + ((ua >> 16) & 1u)) >> 16;
  ub = (ub + 0x7FFFu + ((ub >> 16) & 1u)) & 0xFFFF0000u;
  return ub | ua;
}

__device__ __forceinline__ bf16x8 to_bf16x8(float4 a, float4 b) {
  union { bf16x8 v; unsigned u[4]; } r;
  r.u[0] = pack_bf16(a.x, a.y);
  r.u[1] = pack_bf16(a.z, a.w);
  r.u[2] = pack_bf16(b.x, b.y);
  r.u[3] = pack_bf16(b.z, b.w);
  return r.v;
}

// ---------------- tables (10 blocks x 256) ----------------
// blocks 0..7: ev[ty]/vemb[ty] (Wv @ emb rows)
// block 8: wq_eff/wk_eff in LDS -> Wvh rows 128..143 (bf16) + a_et/aqt/akt
// block 9: Wv -> Wvh rows 0..127 (bf16)
__global__ __launch_bounds__(256) void k_tables(
    const float* __restrict__ Wq, const float* __restrict__ Wk,
    const float* __restrict__ Wv,
    const float* __restrict__ att_i, const float* __restrict__ att_j,
    const float* __restrict__ nemb, const float* __restrict__ eemb,
    float* __restrict__ ev, float* __restrict__ vemb,
    float* __restrict__ a_et, float* __restrict__ aqt, float* __restrict__ akt,
    unsigned* __restrict__ Wvh) {
  int b = blockIdx.x, t = threadIdx.x;
  if (b < 8) {
    __shared__ float er[128], nr[128];
    if (t < 128) { er[t] = eemb[b * D + t]; nr[t] = nemb[b * D + t]; }
    __syncthreads();
    int o = t & 127;
    const float* __restrict__ wr = Wv + (size_t)o * D;
    const float* src = (t < 128) ? er : nr;
    float s = 0.f;
#pragma unroll 8
    for (int d = 0; d < D; ++d) s = fmaf(wr[d], src[d], s);
    if (t < 128) ev[b * D + o] = s;
    else         vemb[b * D + o] = s;
  } else if (b == 8) {
    __shared__ float w_s[1024];  // [0..511]=wq_eff rows 0..3, [512..1023]=wk_eff
    for (int j = t; j < 1024; j += 256) {
      int isq = (j < 512);
      int h = (j >> 7) & 3, d = j & 127;
      const float* __restrict__ Wm = isq ? Wq : Wk;
      const float* __restrict__ am = isq ? att_i : att_j;
      float s = 0.f;
#pragma unroll
      for (int c = 0; c < NC; ++c) s = fmaf(am[h * NC + c], Wm[(h * NC + c) * D + d], s);
      w_s[j] = s;
    }
    __syncthreads();
    // Wvh rows 128..143: rows 0..7 = weff, 8..15 = zero
    for (int j = t; j < 1024; j += 256) {
      int r = j >> 6;
      int c2 = (j & 63) * 2;
      float a = 0.f, bb = 0.f;
      if (r < 8) { a = w_s[r * 128 + c2]; bb = w_s[r * 128 + c2 + 1]; }
      Wvh[(128 + r) * 64 + (j & 63)] = pack_bf16(a, bb);
    }
    if (t < 96) {
      int grp = t >> 5, u = t & 31;
      int ty = u >> 2, hh = u & 3;
      const float* wrow = (grp == 1) ? (w_s + hh * 128) : (w_s + 512 + hh * 128);
      const float* __restrict__ emb = (grp == 0) ? (eemb + ty * D) : (nemb + ty * D);
      float s = 0.f;
#pragma unroll 8
      for (int d = 0; d < D; ++d) s = fmaf(wrow[d], emb[d], s);
      if (grp == 0)      a_et[u] = s;
      else if (grp == 1) aqt[u] = s;
      else               akt[u] = s;
    }
  } else {
    for (int j = t; j < 8192; j += 256) {
      Wvh[j] = pack_bf16(Wv[2 * j], Wv[2 * j + 1]);
    }
  }
}

// ---------------- CSR build ----------------
// hist: 4 edges/thread, records rank (atomic return) for atomic-free scatter
__global__ void k_hist(const int* __restrict__ ei, int* __restrict__ counts,
                       int* __restrict__ rank) {
  int i = blockIdx.x * blockDim.x + threadIdx.x;
  if (i >= NE / 4) return;
  int4 d4 = ((const int4*)(ei + NE))[i];
  int4 r;
  r.x = atomicAdd(&counts[d4.x], 1);
  r.y = atomicAdd(&counts[d4.y], 1);
  r.z = atomicAdd(&counts[d4.z], 1);
  r.w = atomicAdd(&counts[d4.w], 1);
  ((int4*)rank)[i] = r;
}

// single block, 1024 threads, shuffle-scan (2 barriers). Threads 0..999 own 40 nodes.
__global__ __launch_bounds__(1024) void k_scan(const int* __restrict__ counts,
                                               int* __restrict__ rowptr) {
  __shared__ int wsum[16];
  int t = threadIdx.x;
  int lane = t & 63, wv = t >> 6;
  int local[40];
  int total = 0;
  if (t < 1000) {
    const int4* __restrict__ cp = (const int4*)(counts + t * 40);
#pragma unroll
    for (int j = 0; j < 10; ++j) {
      int4 c = cp[j];
      local[4 * j + 0] = total; total += c.x + 1;  // +1 self-loop
      local[4 * j + 1] = total; total += c.y + 1;
      local[4 * j + 2] = total; total += c.z + 1;
      local[4 * j + 3] = total; total += c.w + 1;
    }
  }
  int inc = total;
#pragma unroll
  for (int off = 1; off < 64; off <<= 1) {
    int v = __shfl_up(inc, off, 64);
    if (lane >= off) inc += v;
  }
  if (lane == 63) wsum[wv] = inc;
  __syncthreads();
  if (wv == 0 && lane < 16) {
    int o = wsum[lane];
    int s = o;
#pragma unroll
    for (int off = 1; off < 16; off <<= 1) {
      int v = __shfl_up(s, off, 16);
      if (lane >= off) s += v;
    }
    wsum[lane] = s - o;  // exclusive wave offset
  }
  __syncthreads();
  int offset = wsum[wv] + inc - total;  // exclusive for this thread
  if (t < 1000) {
    int base = t * 40;
#pragma unroll
    for (int j = 0; j < 40; ++j) rowptr[base + j] = offset + local[j];
    if (t == 999) rowptr[NN] = offset + total;  // = NTOT
  }
}

// scatter: atomic-free. edge e -> rowptr[dst]+rank[e]; self-loop n -> rowptr[n+1]-1
__global__ void k_scatter(const int* __restrict__ ei, const int* __restrict__ etype,
                          const int* __restrict__ rowptr, const int* __restrict__ rank,
                          unsigned* __restrict__ packed) {
  int i = blockIdx.x * blockDim.x + threadIdx.x;
  if (i < NE / 4) {
    int4 s4 = ((const int4*)ei)[i];
    int4 d4 = ((const int4*)(ei + NE))[i];
    int4 t4 = ((const int4*)etype)[i];
    int4 r4 = ((const int4*)rank)[i];
    packed[rowptr[d4.x] + r4.x] = (unsigned)s4.x | ((unsigned)t4.x << 16);
    packed[rowptr[d4.y] + r4.y] = (unsigned)s4.y | ((unsigned)t4.y << 16);
    packed[rowptr[d4.z] + r4.z] = (unsigned)s4.z | ((unsigned)t4.z << 16);
    packed[rowptr[d4.w] + r4.w] = (unsigned)s4.w | ((unsigned)t4.w << 16);
  } else if (i < NE / 4 + NN) {
    int n = i - NE / 4;
    packed[rowptr[n + 1] - 1] = (unsigned)n;  // EDGE_TYPE_SELF = 0
  }
}

// ---------------- V projection + aq/ak via MFMA (no LDS, bf16 B preconverted) --
// Block = 4 waves; wave owns 16 nodes. 9 tiles: 0..7 = Wv channels, 8 = weff.
// A: m=lane&15, k=quad*8+j (fp32->bf16 inline). B: direct bf16x8 loads from Wvh.
// C/D: col=lane&15, row=quad*4+reg.
__global__ __launch_bounds__(256) void k_xv(const float* __restrict__ x,
        const int* __restrict__ node_type, const unsigned* __restrict__ Wvh,
        const float* __restrict__ vemb,
        const float* __restrict__ aqt, const float* __restrict__ akt,
        unsigned* __restrict__ xvh, float* __restrict__ aq, float* __restrict__ ak) {
  int t = threadIdx.x;
  int w = t >> 6, l = t & 63;
  int quad = l >> 4, col = l & 15;
  int n0w = blockIdx.x * 64 + w * 16;  // 40000 = 625*64
  const float4* __restrict__ xr = (const float4*)(x + (size_t)(n0w + col) * D);
  bf16x8 afr[4];
#pragma unroll
  for (int s = 0; s < 4; ++s) {
    const float4* p = xr + s * 8 + quad * 2;
    afr[s] = to_bf16x8(p[0], p[1]);
  }
  f32x4 acc[9];
#pragma unroll
  for (int ct = 0; ct < 9; ++ct) acc[ct] = (f32x4){0.f, 0.f, 0.f, 0.f};
#pragma unroll
  for (int ct = 0; ct < 9; ++ct) {
    const unsigned* __restrict__ brow = Wvh + (size_t)(ct * 16 + col) * 64;
#pragma unroll
    for (int s = 0; s < 4; ++s) {
      bf16x8 bfr = *(const bf16x8*)(brow + s * 16 + quad * 4);
      acc[ct] = __builtin_amdgcn_mfma_f32_16x16x32_bf16(afr[s], bfr, acc[ct], 0, 0, 0);
    }
  }
  int nodes[4]; int ntv[4];
#pragma unroll
  for (int r = 0; r < 4; ++r) {
    nodes[r] = n0w + quad * 4 + r;
    ntv[r] = node_type[nodes[r]];
  }
#pragma unroll
  for (int ct = 0; ct < 8; ++ct) {
    int c = ct * 16 + col;
#pragma unroll
    for (int r = 0; r < 4; ++r) {
      float val = acc[ct][r] + vemb[ntv[r] * D + c];
      float pv = __shfl_xor(val, 1);
      if (!(col & 1)) {
        xvh[nodes[r] * 64 + ct * 8 + (col >> 1)] = pack_bf16(val, pv);
      }
    }
  }
  if (col < 4) {
#pragma unroll
    for (int r = 0; r < 4; ++r)
      aq[nodes[r] * NH + col] = acc[8][r] + aqt[ntv[r] * NH + col];
  } else if (col < 8) {
#pragma unroll
    for (int r = 0; r < 4; ++r)
      ak[nodes[r] * NH + (col - 4)] = acc[8][r] + akt[ntv[r] * NH + (col - 4)];
  }
}

// ---------------- gather: one wave per dst, 4-way edge split, bf16 xv ----
// lane group g=l>>4 handles edges e0+g, e0+g+4, ...; lane q=l&15 owns ch 8q..8q+7.
__global__ __launch_bounds__(256) void k_gather(const int* __restrict__ rowptr,
        const unsigned* __restrict__ packed,
        const float* __restrict__ aq, const float* __restrict__ ak,
        const float* __restrict__ a_et, const unsigned* __restrict__ xvh,
        const float* __restrict__ ev, const float* __restrict__ bias,
        float* __restrict__ out) {
  int n = (int)((blockIdx.x * blockDim.x + threadIdx.x) >> 6);
  int l = threadIdx.x & 63;
  if (n >= NN) return;
  int g = l >> 4, q = l & 15;
  int h = q >> 2;
  float aqh = aq[n * NH + h];
  int e0 = rowptr[n], e1 = rowptr[n + 1];
  const uint4* __restrict__ xv4 = (const uint4*)xvh;  // row = 16 uint4
  float acc0 = 0.f, acc1 = 0.f, acc2 = 0.f, acc3 = 0.f;
  float acc4 = 0.f, acc5 = 0.f, acc6 = 0.f, acc7 = 0.f, dsum = 0.f;
  int deg = e1 - e0;
  int iters = (deg + 3) >> 2;
  int e = e0 + g;
  bool val = (e < e1);
  unsigned rec = packed[val ? e : e0];
  int src = (int)(rec & 0xFFFFu), et = (int)(rec >> 16);
  float sA = ak[src * NH + h] + a_et[et * NH + h];
  uint4 vb = xv4[src * 16 + q];
  const float* evp = ev + et * D + 8 * q;
  float4 ea = *(const float4*)evp, eb = *(const float4*)(evp + 4);
  for (int it = 0; it < iters; ++it) {
    int e2 = e + 4;
    bool v2 = (e2 < e1);
    float sA2 = 0.f; uint4 vb2 = make_uint4(0, 0, 0, 0);
    float4 ea2 = make_float4(0.f, 0.f, 0.f, 0.f);
    float4 eb2 = make_float4(0.f, 0.f, 0.f, 0.f);
    if (it + 1 < iters) {  // wave-uniform
      unsigned rec2 = packed[v2 ? e2 : e0];
      int s2 = (int)(rec2 & 0xFFFFu), t2 = (int)(rec2 >> 16);
      sA2 = ak[s2 * NH + h] + a_et[t2 * NH + h];
      vb2 = xv4[s2 * 16 + q];
      const float* ep2 = ev + t2 * D + 8 * q;
      ea2 = *(const float4*)ep2; eb2 = *(const float4*)(ep2 + 4);
    }
    float s = aqh + sA;
    s = (s > 0.f) ? s : NEG * s;
    float p = val ? __expf(s) : 0.f;
    float f0 = __uint_as_float(vb.x << 16);
    float f1 = __uint_as_float(vb.x & 0xFFFF0000u);
    float f2 = __uint_as_float(vb.y << 16);
    float f3 = __uint_as_float(vb.y & 0xFFFF0000u);
    float f4 = __uint_as_float(vb.z << 16);
    float f5 = __uint_as_float(vb.z & 0xFFFF0000u);
    float f6 = __uint_as_float(vb.w << 16);
    float f7 = __uint_as_float(vb.w & 0xFFFF0000u);
    acc0 = fmaf(p, f0 + ea.x, acc0);
    acc1 = fmaf(p, f1 + ea.y, acc1);
    acc2 = fmaf(p, f2 + ea.z, acc2);
    acc3 = fmaf(p, f3 + ea.w, acc3);
    acc4 = fmaf(p, f4 + eb.x, acc4);
    acc5 = fmaf(p, f5 + eb.y, acc5);
    acc6 = fmaf(p, f6 + eb.z, acc6);
    acc7 = fmaf(p, f7 + eb.w, acc7);
    dsum += p;
    e = e2; val = v2; sA = sA2; vb = vb2; ea = ea2; eb = eb2;
  }
  acc0 += __shfl_xor(acc0, 16); acc0 += __shfl_xor(acc0, 32);
  acc1 += __shfl_xor(acc1, 16); acc1 += __shfl_xor(acc1, 32);
  acc2 += __shfl_xor(acc2, 16); acc2 += __shfl_xor(acc2, 32);
  acc3 += __shfl_xor(acc3, 16); acc3 += __shfl_xor(acc3, 32);
  acc4 += __shfl_xor(acc4, 16); acc4 += __shfl_xor(acc4, 32);
  acc5 += __shfl_xor(acc5, 16); acc5 += __shfl_xor(acc5, 32);
  acc6 += __shfl_xor(acc6, 16); acc6 += __shfl_xor(acc6, 32);
  acc7 += __shfl_xor(acc7, 16); acc7 += __shfl_xor(acc7, 32);
  dsum += __shfl_xor(dsum, 16); dsum += __shfl_xor(dsum, 32);
  if (g == 0) {
    float inv = 1.f / (dsum + 1e-16f);
    const float4 b0 = *(const float4*)(bias + 8 * q);
    const float4 b1 = *(const float4*)(bias + 8 * q + 4);
    float4 o0 = make_float4(acc0 * inv + b0.x, acc1 * inv + b0.y,
                            acc2 * inv + b0.z, acc3 * inv + b0.w);
    float4 o1 = make_float4(acc4 * inv + b1.x, acc5 * inv + b1.y,
                            acc6 * inv + b1.z, acc7 * inv + b1.w);
    float4* op = (float4*)(out + (size_t)n * D + 8 * q);
    op[0] = o0; op[1] = o1;
  }
}

extern "C" void kernel_launch(void* const* d_in, const int* in_sizes, int n_in,
                              void* d_out, int out_size, void* d_ws, size_t ws_size,
                              hipStream_t stream) {
  const float* x      = (const float*)d_in[0];
  const int*   ei     = (const int*)d_in[1];
  const int*   ntype  = (const int*)d_in[2];
  const int*   etype  = (const int*)d_in[3];
  const float* Wq     = (const float*)d_in[4];
  const float* Wk     = (const float*)d_in[5];
  const float* Wv     = (const float*)d_in[6];
  const float* att_i  = (const float*)d_in[7];
  const float* att_j  = (const float*)d_in[8];
  const float* bias   = (const float*)d_in[9];
  const float* nemb   = (const float*)d_in[10];
  const float* eemb   = (const float*)d_in[11];
  float* out = (float*)d_out;

  float* ws     = (float*)d_ws;
  unsigned* xvh = (unsigned*)ws;               // NN*64 uints (bf16 pairs)
  float* aq     = ws + (size_t)NN * 64;        // NN*4
  float* ak     = aq + NN * NH;                // NN*4
  float* ev     = ak + NN * NH;                // 1024
  float* vemb   = ev + 1024;                   // 1024
  float* a_et   = vemb + 1024;                 // 32
  float* aqt    = a_et + 32;                   // 32
  float* akt    = aqt + 32;                    // 32
  unsigned* Wvh = (unsigned*)(akt + 32);       // 144*64 = 9216 uints (bf16 pairs)
  int*   counts = (int*)(Wvh + 9216);          // NN
  int*   rowptr = counts + NN;                 // NN+1 (padded to NN+16 for alignment)
  int*   rank   = rowptr + NN + 16;            // NE
  unsigned* packed = (unsigned*)(rank + NE);   // NTOT

  hipMemsetAsync(counts, 0, NN * sizeof(int), stream);
  k_tables<<<dim3(10), dim3(256), 0, stream>>>(Wq, Wk, Wv, att_i, att_j, nemb, eemb,
                                               ev, vemb, a_et, aqt, akt, Wvh);
  k_hist<<<dim3((NE / 4 + 255) / 256), dim3(256), 0, stream>>>(ei, counts, rank);
  k_scan<<<dim3(1), dim3(1024), 0, stream>>>(counts, rowptr);
  k_scatter<<<dim3((NE / 4 + NN + 255) / 256), dim3(256), 0, stream>>>(ei, etype, rowptr, rank, packed);
  k_xv<<<dim3(625), dim3(256), 0, stream>>>(x, ntype, Wvh, vemb, aqt, akt, xvh, aq, ak);
  k_gather<<<dim3((NN + 3) / 4), dim3(256), 0, stream>>>(rowptr, packed, aq, ak, a_et,
                                                         xvh, ev, bias, out);
}